// Round 1
// baseline (476.824 us; speedup 1.0000x reference)
//
#include <hip/hip_runtime.h>
#include <stdint.h>
#include <stddef.h>

using bf16x8 = __attribute__((ext_vector_type(8))) short;
using f32x4  = __attribute__((ext_vector_type(4))) float;

#define DEV static __device__ __forceinline__

DEV unsigned short f2bf(float f) {
  union { float f; uint32_t u; } x; x.f = f;
  uint32_t u = x.u;
  u += 0x7fffu + ((u >> 16) & 1u);   // RNE
  return (unsigned short)(u >> 16);
}

DEV void gld_lds16(const void* g, void* lds) {
  // direct global->LDS, 16B/lane; LDS dest = wave-uniform base + lane*16
  __builtin_amdgcn_global_load_lds(
      (__attribute__((address_space(1))) void*)(uintptr_t)g,
      (__attribute__((address_space(3))) void*)(uintptr_t)lds, 16, 0, 0);
}

// -------- weight transpose: fp32 [K][N] -> bf16 [N][K] --------
__global__ void transpose_w(const float* __restrict__ in, unsigned short* __restrict__ out,
                            int K, int N) {
  __shared__ float tile[64][65];
  int n0 = blockIdx.x * 64, k0 = blockIdx.y * 64;
  int tx = threadIdx.x & 15, ty = threadIdx.x >> 4;
#pragma unroll
  for (int j = 0; j < 4; ++j) {
    int r = ty + j * 16;
    float4 v = *(const float4*)(in + (size_t)(k0 + r) * N + n0 + tx * 4);
    tile[r][tx * 4 + 0] = v.x; tile[r][tx * 4 + 1] = v.y;
    tile[r][tx * 4 + 2] = v.z; tile[r][tx * 4 + 3] = v.w;
  }
  __syncthreads();
#pragma unroll
  for (int j = 0; j < 4; ++j) {
    int n = ty + j * 16;
    ushort4 o;
    o.x = f2bf(tile[tx * 4 + 0][n]);
    o.y = f2bf(tile[tx * 4 + 1][n]);
    o.z = f2bf(tile[tx * 4 + 2][n]);
    o.w = f2bf(tile[tx * 4 + 3][n]);
    *(ushort4*)(out + (size_t)(n0 + n) * K + k0 + tx * 4) = o;
  }
}

__global__ void pack_bias(const float* __restrict__ q, const float* __restrict__ k,
                          const float* __restrict__ v, float* __restrict__ out) {
  int i = blockIdx.x * 256 + threadIdx.x;   // 0..2303
  const float* s = (i < 768) ? q : ((i < 1536) ? k : v);
  int r = i; if (r >= 1536) r -= 1536; else if (r >= 768) r -= 768;
  out[i] = s[r];
}

// -------- LayerNorm: wave per row, fp32 in -> bf16 out --------
__global__ void ln_rows(const float* __restrict__ in, const float* __restrict__ w,
                        const float* __restrict__ b, unsigned short* __restrict__ out) {
  int lane = threadIdx.x & 63;
  int row = blockIdx.x * 4 + (threadIdx.x >> 6);
  const float* p = in + (size_t)row * 768;
  float4 v[3];
  float s = 0.f, s2 = 0.f;
#pragma unroll
  for (int j = 0; j < 3; ++j) {
    v[j] = *(const float4*)(p + j * 256 + lane * 4);
    s  += v[j].x + v[j].y + v[j].z + v[j].w;
    s2 += v[j].x * v[j].x + v[j].y * v[j].y + v[j].z * v[j].z + v[j].w * v[j].w;
  }
#pragma unroll
  for (int o = 32; o >= 1; o >>= 1) { s += __shfl_xor(s, o); s2 += __shfl_xor(s2, o); }
  float mu = s * (1.f / 768.f);
  float var = s2 * (1.f / 768.f) - mu * mu;
  float rs = rsqrtf(var + 1e-6f);
#pragma unroll
  for (int j = 0; j < 3; ++j) {
    int c = j * 256 + lane * 4;
    float4 wv = *(const float4*)(w + c);
    float4 bv = *(const float4*)(b + c);
    ushort4 o4;
    o4.x = f2bf((v[j].x - mu) * rs * wv.x + bv.x);
    o4.y = f2bf((v[j].y - mu) * rs * wv.y + bv.y);
    o4.z = f2bf((v[j].z - mu) * rs * wv.z + bv.z);
    o4.w = f2bf((v[j].w - mu) * rs * wv.w + bv.w);
    *(ushort4*)(out + (size_t)row * 768 + c) = o4;
  }
}

// -------- GEMM: C[M,N] = A[M,K](bf16) * BT[N,K]^T (bf16) + bias, epilogues --------
// EP 0: QKV scatter  1: Oproj(*lam1+resid->f32)  2: FC1+GELU->bf16  3: FC2(*lam2+hidden2->f32)
template <int EP>
__global__ void gemm_bf16(const unsigned short* __restrict__ A,
                          const unsigned short* __restrict__ BT,
                          const float* __restrict__ bias,
                          int N, int K,
                          void* __restrict__ out,
                          const float* __restrict__ scale,
                          const float* __restrict__ addv,
                          unsigned short* __restrict__ q_out,
                          unsigned short* __restrict__ k_out,
                          unsigned short* __restrict__ vt_out) {
  __shared__ unsigned short As[128 * 32];
  __shared__ unsigned short Bs[128 * 32];
  const int wid = threadIdx.x >> 6, lane = threadIdx.x & 63;
  const int bm = blockIdx.y * 128, bn = blockIdx.x * 128;
  const int wr = wid >> 1, wc = wid & 1;
  f32x4 acc[4][4] = {};

  for (int k0 = 0; k0 < K; k0 += 32) {
#pragma unroll
    for (int j = 0; j < 2; ++j) {
      int seg = wid * 2 + j;                 // 0..7, wave-uniform
      int row = seg * 16 + (lane >> 2);      // tile row 0..127
      int kc = k0 + (lane & 3) * 8;          // 8 bf16 = 16B per lane
      gld_lds16(A  + (size_t)(bm + row) * K + kc, (char*)As + seg * 1024);
      gld_lds16(BT + (size_t)(bn + row) * K + kc, (char*)Bs + seg * 1024);
    }
    __syncthreads();   // drains vmcnt -> LDS valid
    bf16x8 af[4], bfr[4];
#pragma unroll
    for (int i = 0; i < 4; ++i)
      af[i] = *(const bf16x8*)(As + (wr * 64 + i * 16 + (lane & 15)) * 32 + (lane >> 4) * 8);
#pragma unroll
    for (int i = 0; i < 4; ++i)
      bfr[i] = *(const bf16x8*)(Bs + (wc * 64 + i * 16 + (lane & 15)) * 32 + (lane >> 4) * 8);
#pragma unroll
    for (int mi = 0; mi < 4; ++mi)
#pragma unroll
      for (int ni = 0; ni < 4; ++ni)
        acc[mi][ni] = __builtin_amdgcn_mfma_f32_16x16x32_bf16(af[mi], bfr[ni], acc[mi][ni], 0, 0, 0);
    __syncthreads();
  }

#pragma unroll
  for (int mi = 0; mi < 4; ++mi) {
#pragma unroll
    for (int ni = 0; ni < 4; ++ni) {
      int col = bn + wc * 64 + ni * 16 + (lane & 15);
      float bcol = bias[col];
#pragma unroll
      for (int r = 0; r < 4; ++r) {
        int row = bm + wr * 64 + mi * 16 + (lane >> 4) * 4 + r;
        float v = acc[mi][ni][r] + bcol;
        if (EP == 0) {
          int b = row >> 10, s = row & 1023;
          int piece = col / 768;
          int rc = col - piece * 768;
          int h = rc >> 6, d = rc & 63;
          unsigned short bvv = f2bf(v);
          if (piece == 0)      q_out [((size_t)(b * 12 + h) * 1024 + s) * 64 + d] = bvv;
          else if (piece == 1) k_out [((size_t)(b * 12 + h) * 1024 + s) * 64 + d] = bvv;
          else                 vt_out[((size_t)(b * 12 + h) * 64 + d) * 1024 + s] = bvv;
        } else if (EP == 1) {
          ((float*)out)[(size_t)row * 768 + col] = v * scale[col] + addv[(size_t)row * 768 + col];
        } else if (EP == 2) {
          float g = 0.5f * v * (1.f + erff(v * 0.70710678118654752f));
          ((unsigned short*)out)[(size_t)row * (size_t)N + col] = f2bf(g);
        } else {
          ((float*)out)[(size_t)row * 768 + col] = v * scale[col] + addv[(size_t)row * 768 + col];
        }
      }
    }
  }
}

// -------- flash attention: Q [B,H,S,D], K [B,H,S,D], V^T [B,H,D,S] -> ctx [B,S,C] bf16 --------
__global__ void attn_fwd(const unsigned short* __restrict__ qb,
                         const unsigned short* __restrict__ kb,
                         const unsigned short* __restrict__ vtb,
                         unsigned short* __restrict__ ctx) {
  __shared__ unsigned short Ks[64 * 64];    // [kv][d], rows XOR-swizzled
  __shared__ unsigned short VTs[64 * 64];   // [d][kv], rows XOR-swizzled
  __shared__ unsigned short Ps[4][16 * 64]; // per-wave P [q][kv], swizzled
  const int wid = threadIdx.x >> 6, lane = threadIdx.x & 63;
  const int bh = blockIdx.y;                       // 0..95
  const int q0 = blockIdx.x * 64 + wid * 16;
  const unsigned short* qh  = qb  + (size_t)bh * 1024 * 64;
  const unsigned short* kh  = kb  + (size_t)bh * 1024 * 64;
  const unsigned short* vth = vtb + (size_t)bh * 64 * 1024;

  bf16x8 qf[2];
#pragma unroll
  for (int kk = 0; kk < 2; ++kk)
    qf[kk] = *(const bf16x8*)(qh + (size_t)(q0 + (lane & 15)) * 64 + kk * 32 + (lane >> 4) * 8);

  f32x4 o_acc[4] = {};
  float m_run[4], l_run[4];
#pragma unroll
  for (int r = 0; r < 4; ++r) { m_run[r] = -INFINITY; l_run[r] = 0.f; }
  const float sc = 0.125f * 1.44269504088896f;   // log2(e)/sqrt(D)

  for (int s0 = 0; s0 < 1024; s0 += 64) {
    // stage K and V^T tiles (reg-staged so we can XOR-swizzle; rule 21)
#pragma unroll
    for (int j = 0; j < 2; ++j) {
      int seg = threadIdx.x + j * 256;          // 0..511
      int row = seg >> 3;
      int bc  = (seg & 7) * 16;
      int bcs = bc ^ ((row & 7) << 4);
      *(uint4*)((char*)Ks  + row * 128 + bcs) = *(const uint4*)(kh  + (size_t)(s0 + row) * 64 + (seg & 7) * 8);
      *(uint4*)((char*)VTs + row * 128 + bcs) = *(const uint4*)(vth + (size_t)row * 1024 + s0 + (seg & 7) * 8);
    }
    __syncthreads();

    // S = Q K^T
    f32x4 s_acc[4] = {};
#pragma unroll
    for (int kk = 0; kk < 2; ++kk) {
#pragma unroll
      for (int nt = 0; nt < 4; ++nt) {
        int row = nt * 16 + (lane & 15);
        int off = (kk * 64 + (lane >> 4) * 16) ^ ((row & 7) << 4);
        bf16x8 kf = *(const bf16x8*)((const char*)Ks + row * 128 + off);
        s_acc[nt] = __builtin_amdgcn_mfma_f32_16x16x32_bf16(qf[kk], kf, s_acc[nt], 0, 0, 0);
      }
    }
    // online softmax (log2 domain)
    float mt[4], alpha[4];
#pragma unroll
    for (int r = 0; r < 4; ++r) {
      float mm = fmaxf(fmaxf(s_acc[0][r], s_acc[1][r]), fmaxf(s_acc[2][r], s_acc[3][r]));
#pragma unroll
      for (int o = 8; o >= 1; o >>= 1) mm = fmaxf(mm, __shfl_xor(mm, o, 16));
      mt[r] = mm * sc;
      float mn = fmaxf(m_run[r], mt[r]);
      alpha[r] = exp2f(m_run[r] - mn);
      m_run[r] = mn;
    }
    float p[4][4];
#pragma unroll
    for (int nt = 0; nt < 4; ++nt)
#pragma unroll
      for (int r = 0; r < 4; ++r)
        p[nt][r] = exp2f(s_acc[nt][r] * sc - m_run[r]);
#pragma unroll
    for (int r = 0; r < 4; ++r) {
      float su = p[0][r] + p[1][r] + p[2][r] + p[3][r];
#pragma unroll
      for (int o = 8; o >= 1; o >>= 1) su += __shfl_xor(su, o, 16);
      l_run[r] = l_run[r] * alpha[r] + su;
    }
    // P -> per-wave LDS (swizzled), then reload as A-fragments
    unsigned short* pw = Ps[wid];
#pragma unroll
    for (int nt = 0; nt < 4; ++nt)
#pragma unroll
      for (int r = 0; r < 4; ++r) {
        int qrow = (lane >> 4) * 4 + r;
        int bc = (nt * 16 + (lane & 15)) * 2;
        *(unsigned short*)((char*)pw + qrow * 128 + (bc ^ ((qrow & 7) << 4))) = f2bf(p[nt][r]);
      }
    asm volatile("s_waitcnt lgkmcnt(0)" ::: "memory");
#pragma unroll
    for (int dt = 0; dt < 4; ++dt)
#pragma unroll
      for (int r = 0; r < 4; ++r)
        o_acc[dt][r] = o_acc[dt][r] * alpha[r];
#pragma unroll
    for (int kk = 0; kk < 2; ++kk) {
      int prow = lane & 15;
      int poff = (kk * 64 + (lane >> 4) * 16) ^ ((prow & 7) << 4);
      bf16x8 pf = *(const bf16x8*)((const char*)pw + prow * 128 + poff);
#pragma unroll
      for (int dt = 0; dt < 4; ++dt) {
        int vrow = dt * 16 + (lane & 15);
        int voff = (kk * 64 + (lane >> 4) * 16) ^ ((vrow & 7) << 4);
        bf16x8 vf = *(const bf16x8*)((const char*)VTs + vrow * 128 + voff);
        o_acc[dt] = __builtin_amdgcn_mfma_f32_16x16x32_bf16(pf, vf, o_acc[dt], 0, 0, 0);
      }
    }
    __syncthreads();
  }

  int b = bh / 12, h = bh % 12;
#pragma unroll
  for (int r = 0; r < 4; ++r) {
    float inv = 1.f / l_run[r];
    int srow = q0 + (lane >> 4) * 4 + r;
#pragma unroll
    for (int dt = 0; dt < 4; ++dt)
      ctx[((size_t)(b * 1024 + srow)) * 768 + h * 64 + dt * 16 + (lane & 15)] =
          f2bf(o_acc[dt][r] * inv);
  }
}

extern "C" void kernel_launch(void* const* d_in, const int* in_sizes, int n_in,
                              void* d_out, int out_size, void* d_ws, size_t ws_size,
                              hipStream_t stream) {
  const float* hs    = (const float*)d_in[0];
  const float* ln1_w = (const float*)d_in[1];
  const float* ln1_b = (const float*)d_in[2];
  const float* q_w   = (const float*)d_in[3];
  const float* q_b   = (const float*)d_in[4];
  const float* k_w   = (const float*)d_in[5];
  const float* k_b   = (const float*)d_in[6];
  const float* v_w   = (const float*)d_in[7];
  const float* v_b   = (const float*)d_in[8];
  const float* o_w   = (const float*)d_in[9];
  const float* o_b   = (const float*)d_in[10];
  const float* lam1  = (const float*)d_in[11];
  const float* ln2_w = (const float*)d_in[12];
  const float* ln2_b = (const float*)d_in[13];
  const float* fc1_w = (const float*)d_in[14];
  const float* fc1_b = (const float*)d_in[15];
  const float* fc2_w = (const float*)d_in[16];
  const float* fc2_b = (const float*)d_in[17];
  const float* lam2  = (const float*)d_in[18];

  char* ws = (char*)d_ws;
  size_t off = 0;
  auto carve = [&](size_t bytes) { char* p = ws + off; off += (bytes + 255) & ~(size_t)255; return p; };
  unsigned short* wqkv_t = (unsigned short*)carve((size_t)2304 * 768 * 2);
  unsigned short* wo_t   = (unsigned short*)carve((size_t)768 * 768 * 2);
  unsigned short* wfc1_t = (unsigned short*)carve((size_t)3072 * 768 * 2);
  unsigned short* wfc2_t = (unsigned short*)carve((size_t)768 * 3072 * 2);
  float*          bqkv   = (float*)carve(2304 * 4);
  const size_t SB = (size_t)8192 * 768 * 2;              // one bf16 [8192][768] buffer
  char* unionA = carve(4 * SB);                          // x_ln|q|k|vt, later reused as act
  unsigned short* x_ln   = (unsigned short*)unionA;
  unsigned short* q_buf  = (unsigned short*)(unionA + SB);
  unsigned short* k_buf  = (unsigned short*)(unionA + 2 * SB);
  unsigned short* vt_buf = (unsigned short*)(unionA + 3 * SB);
  unsigned short* act    = (unsigned short*)unionA;      // FC1 out (x/q/k/vt dead by then)
  unsigned short* ctx    = (unsigned short*)carve(SB);
  float*          hidden2= (float*)carve((size_t)8192 * 768 * 4);
  unsigned short* y_ln   = (unsigned short*)carve(SB);

  pack_bias<<<dim3(9), dim3(256), 0, stream>>>(q_b, k_b, v_b, bqkv);
  transpose_w<<<dim3(12, 12), dim3(256), 0, stream>>>(q_w, wqkv_t, 768, 768);
  transpose_w<<<dim3(12, 12), dim3(256), 0, stream>>>(k_w, wqkv_t + (size_t)768 * 768, 768, 768);
  transpose_w<<<dim3(12, 12), dim3(256), 0, stream>>>(v_w, wqkv_t + (size_t)2 * 768 * 768, 768, 768);
  transpose_w<<<dim3(12, 12), dim3(256), 0, stream>>>(o_w, wo_t, 768, 768);
  transpose_w<<<dim3(48, 12), dim3(256), 0, stream>>>(fc1_w, wfc1_t, 768, 3072);
  transpose_w<<<dim3(12, 48), dim3(256), 0, stream>>>(fc2_w, wfc2_t, 3072, 768);

  ln_rows<<<dim3(2048), dim3(256), 0, stream>>>(hs, ln1_w, ln1_b, x_ln);
  gemm_bf16<0><<<dim3(18, 64), dim3(256), 0, stream>>>(x_ln, wqkv_t, bqkv, 2304, 768,
      nullptr, nullptr, nullptr, q_buf, k_buf, vt_buf);
  attn_fwd<<<dim3(16, 96), dim3(256), 0, stream>>>(q_buf, k_buf, vt_buf, ctx);
  gemm_bf16<1><<<dim3(6, 64), dim3(256), 0, stream>>>(ctx, wo_t, o_b, 768, 768,
      hidden2, lam1, hs, nullptr, nullptr, nullptr);
  ln_rows<<<dim3(2048), dim3(256), 0, stream>>>(hidden2, ln2_w, ln2_b, y_ln);
  gemm_bf16<2><<<dim3(24, 64), dim3(256), 0, stream>>>(y_ln, wfc1_t, fc1_b, 3072, 768,
      act, nullptr, nullptr, nullptr, nullptr, nullptr);
  gemm_bf16<3><<<dim3(6, 64), dim3(256), 0, stream>>>(act, wfc2_t, fc2_b, 768, 3072,
      d_out, lam2, hidden2, nullptr, nullptr, nullptr);
}